// Round 7
// baseline (127.050 us; speedup 1.0000x reference)
//
#include <hip/hip_runtime.h>
#include <cstdint>
#include <cstddef>

// Problem constants
#define NB   64      // batch
#define NL   1024    // seq len
#define NA   512     // ATT_DIM
#define NE   512     // ENC_DIM (= K of the big GEMM)

typedef __attribute__((ext_vector_type(8))) short bf16x8;        // 8 bf16 = 4 VGPR
typedef __attribute__((ext_vector_type(4))) float f32x4;         // MFMA 16x16 acc
typedef __attribute__((ext_vector_type(4))) unsigned int u32x4;

union PackU { u32x4 u; bf16x8 h; };

__device__ __forceinline__ unsigned short f2bf(float x){
    unsigned int u = __float_as_uint(x);
    u += 0x7FFFu + ((u >> 16) & 1u);      // RNE (inputs are finite)
    return (unsigned short)(u >> 16);
}

// ---------------------------------------------------------------------------
// Kernel 0 (merged prep):
//  blocks [0,128)   : repack W_enc into bf16 MFMA B-fragment order
//                     elem idx (16B) = s*4096 + cw*512 + ks*256 + n*64 + lane
//                     lane l holds B[k=64s+32ks+8*(l>>4)+j][col=64cw+16n+(l&15)]
//  blocks [128,640) : base[b][a] = dh[b]@W_dec[:,a] + b_dec + b_enc + b_cov
// ---------------------------------------------------------------------------
__global__ __launch_bounds__(256) void k_prep(const float* __restrict__ Wenc,
                                              unsigned short* __restrict__ wfrag,
                                              const float* __restrict__ dh,
                                              const float* __restrict__ Wdec,
                                              const float* __restrict__ bdec,
                                              const float* __restrict__ benc,
                                              const float* __restrict__ bcov,
                                              float* __restrict__ base){
    const int bid = blockIdx.x, tid = threadIdx.x;
    if (bid < 128){
        const int g    = bid * 256 + tid;              // 0..32767
        const int lane = g & 63;
        const int n    = (g >> 6) & 3;
        const int ks   = (g >> 8) & 1;
        const int cw   = (g >> 9) & 7;
        const int s    = g >> 12;
        const int col  = cw * 64 + n * 16 + (lane & 15);
        const int kb   = s * 64 + ks * 32 + (lane >> 4) * 8;
        unsigned int w[4];
        #pragma unroll
        for (int p = 0; p < 4; ++p){
            unsigned short lo = f2bf(Wenc[(size_t)(kb + 2*p    ) * NA + col]);
            unsigned short hi = f2bf(Wenc[(size_t)(kb + 2*p + 1) * NA + col]);
            w[p] = (unsigned int)lo | ((unsigned int)hi << 16);
        }
        ((uint4*)wfrag)[g] = make_uint4(w[0], w[1], w[2], w[3]);
    } else {
        const int idx = bid - 128;
        const int b   = idx >> 3;
        const int a0  = (idx & 7) * 64;
        const int al  = tid & 63, kg = tid >> 6;       // 4 k-groups of 128
        __shared__ float h[512];
        __shared__ float ps[4][64];
        h[tid]       = dh[b * 512 + tid];
        h[tid + 256] = dh[b * 512 + tid + 256];
        __syncthreads();
        const float* wp = Wdec + (size_t)(kg * 128) * 512 + a0 + al;
        const float* hp = h + kg * 128;
        float s0 = 0.f, s1 = 0.f, s2 = 0.f, s3 = 0.f;
        #pragma unroll
        for (int k = 0; k < 128; k += 4){
            s0 += hp[k + 0] * wp[(size_t)(k + 0) * 512];
            s1 += hp[k + 1] * wp[(size_t)(k + 1) * 512];
            s2 += hp[k + 2] * wp[(size_t)(k + 2) * 512];
            s3 += hp[k + 3] * wp[(size_t)(k + 3) * 512];
        }
        ps[kg][al] = (s0 + s1) + (s2 + s3);
        __syncthreads();
        if (tid < 64){
            const int a = a0 + tid;
            base[b * 512 + a] = ps[0][tid] + ps[1][tid] + ps[2][tid] + ps[3][tid]
                              + bdec[a] + benc[a] + bcov[a];
        }
    }
}

// ---------------------------------------------------------------------------
// Kernel 1: energy[r] = relu(enc[r]@W_enc + base[b] + cov[r]*W_cov) @ W_full
// R7: BARRIER-FREE all-register K-loop. 256 thr / 4 waves; wave owns
// 64r x 128c (cols disjoint -> B wave-private; A rows shared via L1/L2).
// A loaded DIRECTLY as MFMA fragments (2x float4/lane/frag) + in-reg cvt;
// B loaded straight to regs from pre-packed wfrag (L2-hot). No LDS in the
// K-loop, no __syncthreads, no vmcnt(0) drains: 8 waves/CU TLP hides all
// latency; MFMA pipe is the intended limiter (~16.6us chip-wide).
// ---------------------------------------------------------------------------
__global__ __launch_bounds__(256, 2) void k_energy(
        const float* __restrict__ enc,          // [65536][512]
        const float* __restrict__ cov,          // [65536]
        const float* __restrict__ base,         // [64][512]
        const unsigned short* __restrict__ wfrag,
        const float* __restrict__ Wcov,         // [512]
        const float* __restrict__ Wfull,        // [512]
        float* __restrict__ energy)             // [65536]
{
    __shared__ float sEp[4][64];

    const int tid  = threadIdx.x;
    const int wid  = tid >> 6, lane = tid & 63;
    const int r0   = blockIdx.x * 64;
    const int b    = r0 >> 10;

    // A fragment base: lane l covers row r0+(l&15) (+16 per m), k-off 8*(l>>4)
    const float* aB = enc + (size_t)(r0 + (lane & 15)) * NE + 8 * (lane >> 4);
    // B fragment stream (16B units): s*4096 + cw*512 + ks*256 + n*64 + lane
    const bf16x8* bB = (const bf16x8*)wfrag + (wid * 2) * 512 + lane;

    f32x4 acc[4][8];
    #pragma unroll
    for (int m = 0; m < 4; ++m)
        #pragma unroll
        for (int nn = 0; nn < 8; ++nn) acc[m][nn] = (f32x4){0.f, 0.f, 0.f, 0.f};

    #pragma unroll 1
    for (int s = 0; s < 8; ++s){
        #pragma unroll
        for (int ks = 0; ks < 2; ++ks){
            // B: 8 wave-private fragments (L2-hot)
            bf16x8 bfr[8];
            #pragma unroll
            for (int nn = 0; nn < 8; ++nn)
                bfr[nn] = bB[s * 4096 + (nn >> 2) * 512 + ks * 256 + (nn & 3) * 64];
            // A: 4 fragments, direct load + in-register cvt
            bf16x8 af[4];
            #pragma unroll
            for (int m = 0; m < 4; ++m){
                const float* ap = aB + (size_t)(m * 16) * NE + s * 64 + ks * 32;
                float4 lo = *(const float4*)(ap);
                float4 hi = *(const float4*)(ap + 4);
                PackU u;
                u.u = (u32x4){
                    (unsigned)f2bf(lo.x) | ((unsigned)f2bf(lo.y) << 16),
                    (unsigned)f2bf(lo.z) | ((unsigned)f2bf(lo.w) << 16),
                    (unsigned)f2bf(hi.x) | ((unsigned)f2bf(hi.y) << 16),
                    (unsigned)f2bf(hi.z) | ((unsigned)f2bf(hi.w) << 16)};
                af[m] = u.h;
            }
            // 32 MFMAs
            #pragma unroll
            for (int nn = 0; nn < 8; ++nn)
                #pragma unroll
                for (int m = 0; m < 4; ++m)
                    acc[m][nn] = __builtin_amdgcn_mfma_f32_16x16x32_bf16(
                                    af[m], bfr[nn], acc[m][nn], 0, 0, 0);
        }
    }

    // ---- epilogue: relu(acc + base + cov*Wcov) * Wfull, reduce over cols
    const int c0 = wid * 128 + (lane & 15);
    float basev[8], wcovv[8], wfullv[8];
    #pragma unroll
    for (int nn = 0; nn < 8; ++nn){
        const int c = c0 + (nn >> 2) * 64 + (nn & 3) * 16;
        basev[nn]  = base[b * 512 + c];
        wcovv[nn]  = Wcov[c];
        wfullv[nn] = Wfull[c];
    }
    const int hi4 = lane >> 4;                // D row = m*16 + 4*hi4 + reg
    float covr[4][4];
    #pragma unroll
    for (int m = 0; m < 4; ++m)
        #pragma unroll
        for (int r = 0; r < 4; ++r)
            covr[m][r] = cov[r0 + m * 16 + 4 * hi4 + r];
    float epv[4][4] = {};
    #pragma unroll
    for (int m = 0; m < 4; ++m)
        #pragma unroll
        for (int nn = 0; nn < 8; ++nn)
            #pragma unroll
            for (int r = 0; r < 4; ++r){
                float v = acc[m][nn][r] + basev[nn] + covr[m][r] * wcovv[nn];
                v = fmaxf(v, 0.f);
                epv[m][r] += v * wfullv[nn];
            }
    #pragma unroll
    for (int m = 0; m < 4; ++m)
        #pragma unroll
        for (int r = 0; r < 4; ++r){
            float v = epv[m][r];
            v += __shfl_xor(v, 1);
            v += __shfl_xor(v, 2);
            v += __shfl_xor(v, 4);
            v += __shfl_xor(v, 8);
            epv[m][r] = v;
        }
    if ((lane & 15) == 0){
        #pragma unroll
        for (int m = 0; m < 4; ++m)
            #pragma unroll
            for (int r = 0; r < 4; ++r)
                sEp[wid][m * 16 + 4 * hi4 + r] = epv[m][r];
    }
    __syncthreads();
    if (tid < 64)
        energy[r0 + tid] = sEp[0][tid] + sEp[1][tid] + sEp[2][tid] + sEp[3][tid];
}

// ---------------------------------------------------------------------------
// Kernel 2: softmax over L, alpha/new_coverage writes, weighted encoding.
// float4 weighted-sum loads (16B/lane).
// ---------------------------------------------------------------------------
#define AWE_OFF   0
#define ALPHA_OFF 32768
#define NCOV_OFF  98304

__global__ __launch_bounds__(256) void k_finish(
        const float* __restrict__ enc, const float* __restrict__ cov,
        const float* __restrict__ energy, float* __restrict__ out)
{
    const int bid = blockIdx.x;
    const int b = bid >> 3, ec = bid & 7;
    const int tid = threadIdx.x;
    __shared__ float sa[1024];
    __shared__ float rb[16];
    __shared__ float ps2[16][64];

    float4 ev = ((const float4*)(energy + b * 1024))[tid];
    float mx = fmaxf(fmaxf(ev.x, ev.y), fmaxf(ev.z, ev.w));
    #pragma unroll
    for (int off = 32; off; off >>= 1) mx = fmaxf(mx, __shfl_xor(mx, off));
    if ((tid & 63) == 0) rb[tid >> 6] = mx;
    __syncthreads();
    mx = fmaxf(fmaxf(rb[0], rb[1]), fmaxf(rb[2], rb[3]));
    float e0 = __expf(ev.x - mx), e1 = __expf(ev.y - mx),
          e2 = __expf(ev.z - mx), e3 = __expf(ev.w - mx);
    ((float4*)sa)[tid] = make_float4(e0, e1, e2, e3);
    float sm = e0 + e1 + e2 + e3;
    #pragma unroll
    for (int off = 32; off; off >>= 1) sm += __shfl_xor(sm, off);
    if ((tid & 63) == 0) rb[8 + (tid >> 6)] = sm;
    __syncthreads();
    const float inv = 1.0f / (rb[8] + rb[9] + rb[10] + rb[11]);

    if (ec == 0){
        #pragma unroll
        for (int i = 0; i < 4; ++i){
            const int idx = tid + i * 256;
            const float a = sa[idx] * inv;
            out[ALPHA_OFF + b * 1024 + idx] = a;
            out[NCOV_OFF  + b * 1024 + idx] = cov[b * 1024 + idx] + a;
        }
    }

    // weighted sum: thread = (row-group rg of 64 rows, col-group cg of 4 cols)
    const int cg = tid & 15, rg = tid >> 4;
    const float4* ep = (const float4*)(enc + (size_t)(b * 1024 + rg * 64) * 512)
                     + ec * 16 + cg;
    const float* w = sa + rg * 64;
    float ax = 0.f, ay = 0.f, az = 0.f, aw = 0.f;
    #pragma unroll 8
    for (int l = 0; l < 64; ++l){
        float4 e4 = ep[(size_t)l * 128];
        const float wl = w[l];
        ax += e4.x * wl; ay += e4.y * wl; az += e4.z * wl; aw += e4.w * wl;
    }
    ps2[rg][cg * 4 + 0] = ax;
    ps2[rg][cg * 4 + 1] = ay;
    ps2[rg][cg * 4 + 2] = az;
    ps2[rg][cg * 4 + 3] = aw;
    __syncthreads();
    if (tid < 64){
        float s = 0.f;
        #pragma unroll
        for (int g = 0; g < 16; ++g) s += ps2[g][tid];
        out[AWE_OFF + b * 512 + ec * 64 + tid] = s * inv;
    }
}

// ---------------------------------------------------------------------------
extern "C" void kernel_launch(void* const* d_in, const int* in_sizes, int n_in,
                              void* d_out, int out_size, void* d_ws, size_t ws_size,
                              hipStream_t stream){
    const float* enc   = (const float*)d_in[0];
    const float* dh    = (const float*)d_in[1];
    const float* cov   = (const float*)d_in[2];
    const float* Wenc  = (const float*)d_in[3];
    const float* benc  = (const float*)d_in[4];
    const float* Wdec  = (const float*)d_in[5];
    const float* bdec  = (const float*)d_in[6];
    const float* Wcov  = (const float*)d_in[7];
    const float* bcov  = (const float*)d_in[8];
    const float* Wfull = (const float*)d_in[9];
    // d_in[10] (b_full) unused: softmax is shift-invariant.
    float* out = (float*)d_out;

    unsigned short* wfrag = (unsigned short*)d_ws;              // 512 KB
    float* base   = (float*)((char*)d_ws + 512 * 1024);        // 128 KB
    float* energy = (float*)((char*)d_ws + 640 * 1024);        // 256 KB

    k_prep  <<<640,  256, 0, stream>>>(Wenc, wfrag, dh, Wdec, bdec, benc, bcov, base);
    k_energy<<<1024, 256, 0, stream>>>(enc, cov, base, wfrag, Wcov, Wfull, energy);
    k_finish<<<512,  256, 0, stream>>>(enc, cov, energy, out);
}

// Round 8
// 105.946 us; speedup vs baseline: 1.1992x; 1.1992x over previous
//
#include <hip/hip_runtime.h>
#include <cstdint>
#include <cstddef>

// Problem constants
#define NB   64      // batch
#define NL   1024    // seq len
#define NA   512     // ATT_DIM
#define NE   512     // ENC_DIM (= K of the big GEMM)

typedef __attribute__((ext_vector_type(8))) short bf16x8;  // 8 bf16 = 4 VGPR
typedef __attribute__((ext_vector_type(4))) float f32x4;   // MFMA 16x16 acc

__device__ __forceinline__ unsigned short f2bf(float x){
    unsigned int u = __float_as_uint(x);
    u += 0x7FFFu + ((u >> 16) & 1u);      // RNE (inputs are finite)
    return (unsigned short)(u >> 16);
}

// ---------------------------------------------------------------------------
// Kernel 0 (merged prep):
//  blocks [0,128)   : repack W_enc into bf16 MFMA B-fragment order
//                     elem idx (16B) = s*4096 + cw*512 + ks*256 + n*64 + lane
//                     lane l holds B[k=64s+32ks+8*(l>>4)+j][col=64cw+16n+(l&15)]
//  blocks [128,640) : base[b][a] = dh[b]@W_dec[:,a] + b_dec + b_enc + b_cov
// ---------------------------------------------------------------------------
__global__ __launch_bounds__(256) void k_prep(const float* __restrict__ Wenc,
                                              unsigned short* __restrict__ wfrag,
                                              const float* __restrict__ dh,
                                              const float* __restrict__ Wdec,
                                              const float* __restrict__ bdec,
                                              const float* __restrict__ benc,
                                              const float* __restrict__ bcov,
                                              float* __restrict__ base){
    const int bid = blockIdx.x, tid = threadIdx.x;
    if (bid < 128){
        const int g    = bid * 256 + tid;              // 0..32767
        const int lane = g & 63;
        const int n    = (g >> 6) & 3;
        const int ks   = (g >> 8) & 1;
        const int cw   = (g >> 9) & 7;
        const int s    = g >> 12;
        const int col  = cw * 64 + n * 16 + (lane & 15);
        const int kb   = s * 64 + ks * 32 + (lane >> 4) * 8;
        unsigned int w[4];
        #pragma unroll
        for (int p = 0; p < 4; ++p){
            unsigned short lo = f2bf(Wenc[(size_t)(kb + 2*p    ) * NA + col]);
            unsigned short hi = f2bf(Wenc[(size_t)(kb + 2*p + 1) * NA + col]);
            w[p] = (unsigned int)lo | ((unsigned int)hi << 16);
        }
        ((uint4*)wfrag)[g] = make_uint4(w[0], w[1], w[2], w[3]);
    } else {
        const int idx = bid - 128;
        const int b   = idx >> 3;
        const int a0  = (idx & 7) * 64;
        const int al  = tid & 63, kg = tid >> 6;       // 4 k-groups of 128
        __shared__ float h[512];
        __shared__ float ps[4][64];
        h[tid]       = dh[b * 512 + tid];
        h[tid + 256] = dh[b * 512 + tid + 256];
        __syncthreads();
        const float* wp = Wdec + (size_t)(kg * 128) * 512 + a0 + al;
        const float* hp = h + kg * 128;
        float s0 = 0.f, s1 = 0.f, s2 = 0.f, s3 = 0.f;
        #pragma unroll
        for (int k = 0; k < 128; k += 4){
            s0 += hp[k + 0] * wp[(size_t)(k + 0) * 512];
            s1 += hp[k + 1] * wp[(size_t)(k + 1) * 512];
            s2 += hp[k + 2] * wp[(size_t)(k + 2) * 512];
            s3 += hp[k + 3] * wp[(size_t)(k + 3) * 512];
        }
        ps[kg][al] = (s0 + s1) + (s2 + s3);
        __syncthreads();
        if (tid < 64){
            const int a = a0 + tid;
            base[b * 512 + a] = ps[0][tid] + ps[1][tid] + ps[2][tid] + ps[3][tid]
                              + bdec[a] + benc[a] + bcov[a];
        }
    }
}

// ---------------------------------------------------------------------------
// Kernel 1: energy[r] = relu(enc[r]@W_enc + base[b] + cov[r]*W_cov) @ W_full
// R8: R6 staging + overlapped single-barrier pipeline.
// BM=64, BN=512, 256 thr / 4 waves. LDS: sA dbuf 2x8KB + sB dbuf 2x64KB.
// Step s: issue rawA(s+2)->regs and B(s+1)->global_load_lds->sB[nxt] FIRST;
// then 64 MFMA/wave on [cur]; then cvt rawA loaded at s-1 (vmcnt long since
// satisfied -> stall-free) + ds_write sA[nxt]; ONE barrier. The pre-barrier
// vmcnt(0) drain of B overlaps the ~1240cyc CU-wide MFMA cluster.
// ---------------------------------------------------------------------------
#define LOAD_RAW(av, ap)                                         \
    { av[0] = *(const float4*)(ap);                              \
      av[1] = *(const float4*)((ap) + 4);                        \
      av[2] = *(const float4*)((ap) + 8);                        \
      av[3] = *(const float4*)((ap) + 12); }

#define PACK_STORE(av, dst)                                      \
    { uint4 f1, f2;                                              \
      f1.x = f2bf(av[0].x) | ((unsigned)f2bf(av[0].y) << 16);    \
      f1.y = f2bf(av[0].z) | ((unsigned)f2bf(av[0].w) << 16);    \
      f1.z = f2bf(av[1].x) | ((unsigned)f2bf(av[1].y) << 16);    \
      f1.w = f2bf(av[1].z) | ((unsigned)f2bf(av[1].w) << 16);    \
      f2.x = f2bf(av[2].x) | ((unsigned)f2bf(av[2].y) << 16);    \
      f2.y = f2bf(av[2].z) | ((unsigned)f2bf(av[2].w) << 16);    \
      f2.z = f2bf(av[3].x) | ((unsigned)f2bf(av[3].y) << 16);    \
      f2.w = f2bf(av[3].z) | ((unsigned)f2bf(av[3].w) << 16);    \
      *(uint4*)(dst)       = f1;                                 \
      *(uint4*)((dst)+256) = f2; }

__global__ __launch_bounds__(256, 2) void k_energy(
        const float* __restrict__ enc,          // [65536][512]
        const float* __restrict__ cov,          // [65536]
        const float* __restrict__ base,         // [64][512]
        const unsigned short* __restrict__ wfrag,
        const float* __restrict__ Wcov,         // [512]
        const float* __restrict__ Wfull,        // [512]
        float* __restrict__ energy)             // [65536]
{
    __shared__ __align__(16) unsigned char sB[2][65536]; // [cw(8)][ks(2)][n(4)][lane][16B]
    __shared__ __align__(16) unsigned char sA[2][8192];  // [ks(2)][m(4)][lane][16B]
    __shared__ float sCov[64];
    __shared__ float sEp[4][64];

    const int tid  = threadIdx.x;
    const int wid  = tid >> 6, lane = tid & 63;
    const int r0   = blockIdx.x * 64;
    const int b    = r0 >> 10;

    if (tid < 64) sCov[tid] = cov[r0 + tid];

    f32x4 acc[4][8];
    #pragma unroll
    for (int m = 0; m < 4; ++m)
        #pragma unroll
        for (int n = 0; n < 8; ++n) acc[m][n] = (f32x4){0.f, 0.f, 0.f, 0.f};

    // A staging map: thread t covers row rloc=t>>2, 16 floats at q*16 of a step
    const int rloc = tid >> 2, q = tid & 3;
    const float* arow = enc + (size_t)(r0 + rloc) * NE + q * 16;
    const int awoff = ((q >> 1) * 4 + (rloc >> 4)) * 1024
                    + ((rloc & 15) + 32 * (q & 1)) * 16;
    // B staging: wave stages its own 16KB quarter (cw pair 2wid,2wid+1)
    const unsigned char* bsrc = (const unsigned char*)wfrag + wid * 16384 + lane * 16;

    float4 avA[4], avB[4];

    // ---- prologue: A(0)->sA[0] direct; B(0) glds -> sB[0]; issue A(1)->avB
    {
        float4 p[4];
        LOAD_RAW(p, arow);
        PACK_STORE(p, sA[0] + awoff);
        #pragma unroll
        for (int i = 0; i < 16; ++i){
            __builtin_amdgcn_global_load_lds(
                (__attribute__((address_space(1))) void*)(bsrc + i * 1024),
                (__attribute__((address_space(3))) void*)(sB[0] + wid * 16384 + i * 1024),
                16, 0, 0);
        }
        LOAD_RAW(avB, arow + 64);
    }
    __syncthreads();

    #pragma unroll
    for (int s = 0; s < 8; ++s){
        const int cb = s & 1;
        // ---- phase 1: issue next-next A raw and next B stage
        if (s < 6){
            const float* ap = arow + (s + 2) * 64;
            if ((s & 1) == 0) { LOAD_RAW(avA, ap) }
            else              { LOAD_RAW(avB, ap) }
        }
        if (s < 7){
            const unsigned char* bs = bsrc + (size_t)(s + 1) * 65536;
            unsigned char* bdst = sB[cb ^ 1] + wid * 16384;
            #pragma unroll
            for (int i = 0; i < 16; ++i){
                __builtin_amdgcn_global_load_lds(
                    (__attribute__((address_space(1))) void*)(bs + i * 1024),
                    (__attribute__((address_space(3))) void*)(bdst + i * 1024),
                    16, 0, 0);
            }
        }
        // ---- phase 2: 64 MFMAs / wave on [cur] buffers
        bf16x8 af[2][4];
        #pragma unroll
        for (int ks = 0; ks < 2; ++ks)
            #pragma unroll
            for (int m = 0; m < 4; ++m)
                af[ks][m] = *(const bf16x8*)(sA[cb] + (ks*4 + m) * 1024 + lane * 16);
        #pragma unroll
        for (int ks = 0; ks < 2; ++ks){
            #pragma unroll
            for (int n = 0; n < 8; ++n){
                bf16x8 bfr = *(const bf16x8*)(sB[cb]
                    + ((wid*2 + (n>>2)) * 512 + ks * 256 + (n&3) * 64 + lane) * 16);
                #pragma unroll
                for (int m = 0; m < 4; ++m)
                    acc[m][n] = __builtin_amdgcn_mfma_f32_16x16x32_bf16(
                                    af[ks][m], bfr, acc[m][n], 0, 0, 0);
            }
        }
        // ---- phase 3: cvt the step-old raw A -> sA[nxt] (A(s+1))
        if (s < 7){
            if ((s & 1) == 0) { PACK_STORE(avB, sA[cb ^ 1] + awoff) }
            else              { PACK_STORE(avA, sA[cb ^ 1] + awoff) }
        }
        __syncthreads();
    }

    // ---- epilogue: relu(acc + base + cov*Wcov) * Wfull, reduce over cols
    const int c0 = wid * 128 + (lane & 15);
    float basev[8], wcovv[8], wfullv[8];
    #pragma unroll
    for (int n = 0; n < 8; ++n){
        const int c = c0 + ((n >> 2) * 64) + (n & 3) * 16;
        basev[n]  = base[b * 512 + c];
        wcovv[n]  = Wcov[c];
        wfullv[n] = Wfull[c];
    }
    const int hi = lane >> 4;                 // D row = m*16 + 4*hi + reg
    float covr[4][4];
    #pragma unroll
    for (int m = 0; m < 4; ++m)
        #pragma unroll
        for (int r = 0; r < 4; ++r) covr[m][r] = sCov[m*16 + 4*hi + r];
    float epv[4][4] = {};
    #pragma unroll
    for (int m = 0; m < 4; ++m)
        #pragma unroll
        for (int n = 0; n < 8; ++n)
            #pragma unroll
            for (int r = 0; r < 4; ++r){
                float v = acc[m][n][r] + basev[n] + covr[m][r] * wcovv[n];
                v = fmaxf(v, 0.f);
                epv[m][r] += v * wfullv[n];
            }
    #pragma unroll
    for (int m = 0; m < 4; ++m)
        #pragma unroll
        for (int r = 0; r < 4; ++r){
            float v = epv[m][r];
            v += __shfl_xor(v, 1);
            v += __shfl_xor(v, 2);
            v += __shfl_xor(v, 4);
            v += __shfl_xor(v, 8);
            epv[m][r] = v;
        }
    if ((lane & 15) == 0){
        #pragma unroll
        for (int m = 0; m < 4; ++m)
            #pragma unroll
            for (int r = 0; r < 4; ++r)
                sEp[wid][m*16 + 4*hi + r] = epv[m][r];
    }
    __syncthreads();
    if (tid < 64)
        energy[r0 + tid] = sEp[0][tid] + sEp[1][tid] + sEp[2][tid] + sEp[3][tid];
}

// ---------------------------------------------------------------------------
// Kernel 2: softmax over L, alpha/new_coverage writes, weighted encoding.
// ---------------------------------------------------------------------------
#define AWE_OFF   0
#define ALPHA_OFF 32768
#define NCOV_OFF  98304

__global__ __launch_bounds__(256) void k_finish(
        const float* __restrict__ enc, const float* __restrict__ cov,
        const float* __restrict__ energy, float* __restrict__ out)
{
    const int bid = blockIdx.x;
    const int b = bid >> 3, ec = bid & 7;
    const int tid = threadIdx.x;
    __shared__ float sa[1024];
    __shared__ float rb[16];
    __shared__ float ps2[16][64];

    float4 ev = ((const float4*)(energy + b * 1024))[tid];
    float mx = fmaxf(fmaxf(ev.x, ev.y), fmaxf(ev.z, ev.w));
    #pragma unroll
    for (int off = 32; off; off >>= 1) mx = fmaxf(mx, __shfl_xor(mx, off));
    if ((tid & 63) == 0) rb[tid >> 6] = mx;
    __syncthreads();
    mx = fmaxf(fmaxf(rb[0], rb[1]), fmaxf(rb[2], rb[3]));
    float e0 = __expf(ev.x - mx), e1 = __expf(ev.y - mx),
          e2 = __expf(ev.z - mx), e3 = __expf(ev.w - mx);
    ((float4*)sa)[tid] = make_float4(e0, e1, e2, e3);
    float sm = e0 + e1 + e2 + e3;
    #pragma unroll
    for (int off = 32; off; off >>= 1) sm += __shfl_xor(sm, off);
    if ((tid & 63) == 0) rb[8 + (tid >> 6)] = sm;
    __syncthreads();
    const float inv = 1.0f / (rb[8] + rb[9] + rb[10] + rb[11]);

    if (ec == 0){
        #pragma unroll
        for (int i = 0; i < 4; ++i){
            const int idx = tid + i * 256;
            const float a = sa[idx] * inv;
            out[ALPHA_OFF + b * 1024 + idx] = a;
            out[NCOV_OFF  + b * 1024 + idx] = cov[b * 1024 + idx] + a;
        }
    }

    // weighted sum: thread = (row-group rg of 64 rows, col-group cg of 4 cols)
    const int cg = tid & 15, rg = tid >> 4;
    const float4* ep = (const float4*)(enc + (size_t)(b * 1024 + rg * 64) * 512)
                     + ec * 16 + cg;
    const float* w = sa + rg * 64;
    float ax = 0.f, ay = 0.f, az = 0.f, aw = 0.f;
    #pragma unroll 8
    for (int l = 0; l < 64; ++l){
        float4 e4 = ep[(size_t)l * 128];
        const float wl = w[l];
        ax += e4.x * wl; ay += e4.y * wl; az += e4.z * wl; aw += e4.w * wl;
    }
    ps2[rg][cg * 4 + 0] = ax;
    ps2[rg][cg * 4 + 1] = ay;
    ps2[rg][cg * 4 + 2] = az;
    ps2[rg][cg * 4 + 3] = aw;
    __syncthreads();
    if (tid < 64){
        float s = 0.f;
        #pragma unroll
        for (int g = 0; g < 16; ++g) s += ps2[g][tid];
        out[AWE_OFF + b * 512 + ec * 64 + tid] = s * inv;
    }
}

// ---------------------------------------------------------------------------
extern "C" void kernel_launch(void* const* d_in, const int* in_sizes, int n_in,
                              void* d_out, int out_size, void* d_ws, size_t ws_size,
                              hipStream_t stream){
    const float* enc   = (const float*)d_in[0];
    const float* dh    = (const float*)d_in[1];
    const float* cov   = (const float*)d_in[2];
    const float* Wenc  = (const float*)d_in[3];
    const float* benc  = (const float*)d_in[4];
    const float* Wdec  = (const float*)d_in[5];
    const float* bdec  = (const float*)d_in[6];
    const float* Wcov  = (const float*)d_in[7];
    const float* bcov  = (const float*)d_in[8];
    const float* Wfull = (const float*)d_in[9];
    // d_in[10] (b_full) unused: softmax is shift-invariant.
    float* out = (float*)d_out;

    unsigned short* wfrag = (unsigned short*)d_ws;              // 512 KB
    float* base   = (float*)((char*)d_ws + 512 * 1024);        // 128 KB
    float* energy = (float*)((char*)d_ws + 640 * 1024);        // 256 KB

    k_prep  <<<640,  256, 0, stream>>>(Wenc, wfrag, dh, Wdec, bdec, benc, bcov, base);
    k_energy<<<1024, 256, 0, stream>>>(enc, cov, base, wfrag, Wcov, Wfull, energy);
    k_finish<<<512,  256, 0, stream>>>(enc, cov, energy, out);
}

// Round 9
// 82.260 us; speedup vs baseline: 1.5445x; 1.2879x over previous
//
#include <hip/hip_runtime.h>
#include <cstdint>
#include <cstddef>

// Problem constants
#define NB   64      // batch
#define NL   1024    // seq len
#define NA   512     // ATT_DIM
#define NE   512     // ENC_DIM (= K of the big GEMM)

typedef __attribute__((ext_vector_type(8))) short bf16x8;  // 8 bf16 = 4 VGPR
typedef __attribute__((ext_vector_type(4))) float f32x4;   // MFMA 16x16 acc

__device__ __forceinline__ unsigned short f2bf(float x){
    unsigned int u = __float_as_uint(x);
    u += 0x7FFFu + ((u >> 16) & 1u);      // RNE (inputs are finite)
    return (unsigned short)(u >> 16);
}

__device__ __forceinline__ uint4 pack8(float4 a, float4 b){
    uint4 f;
    f.x = (unsigned)f2bf(a.x) | ((unsigned)f2bf(a.y) << 16);
    f.y = (unsigned)f2bf(a.z) | ((unsigned)f2bf(a.w) << 16);
    f.z = (unsigned)f2bf(b.x) | ((unsigned)f2bf(b.y) << 16);
    f.w = (unsigned)f2bf(b.z) | ((unsigned)f2bf(b.w) << 16);
    return f;
}

// ---------------------------------------------------------------------------
// Kernel 0 (merged prep):
//  blocks [0,128)   : repack W_enc into bf16 MFMA B-fragment order
//                     elem idx (16B) = s*4096 + cw*512 + ks*256 + n*64 + lane
//                     lane l holds B[k=64s+32ks+8*(l>>4)+j][col=64cw+16n+(l&15)]
//  blocks [128,640) : base[b][a] = dh[b]@W_dec[:,a] + b_dec + b_enc + b_cov
// ---------------------------------------------------------------------------
__global__ __launch_bounds__(256) void k_prep(const float* __restrict__ Wenc,
                                              unsigned short* __restrict__ wfrag,
                                              const float* __restrict__ dh,
                                              const float* __restrict__ Wdec,
                                              const float* __restrict__ bdec,
                                              const float* __restrict__ benc,
                                              const float* __restrict__ bcov,
                                              float* __restrict__ base){
    const int bid = blockIdx.x, tid = threadIdx.x;
    if (bid < 128){
        const int g    = bid * 256 + tid;              // 0..32767
        const int lane = g & 63;
        const int n    = (g >> 6) & 3;
        const int ks   = (g >> 8) & 1;
        const int cw   = (g >> 9) & 7;
        const int s    = g >> 12;
        const int col  = cw * 64 + n * 16 + (lane & 15);
        const int kb   = s * 64 + ks * 32 + (lane >> 4) * 8;
        unsigned int w[4];
        #pragma unroll
        for (int p = 0; p < 4; ++p){
            unsigned short lo = f2bf(Wenc[(size_t)(kb + 2*p    ) * NA + col]);
            unsigned short hi = f2bf(Wenc[(size_t)(kb + 2*p + 1) * NA + col]);
            w[p] = (unsigned int)lo | ((unsigned int)hi << 16);
        }
        ((uint4*)wfrag)[g] = make_uint4(w[0], w[1], w[2], w[3]);
    } else {
        const int idx = bid - 128;
        const int b   = idx >> 3;
        const int a0  = (idx & 7) * 64;
        const int al  = tid & 63, kg = tid >> 6;       // 4 k-groups of 128
        __shared__ float h[512];
        __shared__ float ps[4][64];
        h[tid]       = dh[b * 512 + tid];
        h[tid + 256] = dh[b * 512 + tid + 256];
        __syncthreads();
        const float* wp = Wdec + (size_t)(kg * 128) * 512 + a0 + al;
        const float* hp = h + kg * 128;
        float s0 = 0.f, s1 = 0.f, s2 = 0.f, s3 = 0.f;
        #pragma unroll
        for (int k = 0; k < 128; k += 4){
            s0 += hp[k + 0] * wp[(size_t)(k + 0) * 512];
            s1 += hp[k + 1] * wp[(size_t)(k + 1) * 512];
            s2 += hp[k + 2] * wp[(size_t)(k + 2) * 512];
            s3 += hp[k + 3] * wp[(size_t)(k + 3) * 512];
        }
        ps[kg][al] = (s0 + s1) + (s2 + s3);
        __syncthreads();
        if (tid < 64){
            const int a = a0 + tid;
            base[b * 512 + a] = ps[0][tid] + ps[1][tid] + ps[2][tid] + ps[3][tid]
                              + bdec[a] + benc[a] + bcov[a];
        }
    }
}

// ---------------------------------------------------------------------------
// Kernel 1: energy[r] = relu(enc[r]@W_enc + base[b] + cov[r]*W_cov) @ W_full
// R9: BK=32, dbuf BOTH operands at small LDS (72KB -> 2 blocks/CU), ONE
// barrier/step. BM=64, BN=512, 256 thr / 4 waves, wave = 64r x 128c.
// Phase order puts every drain under the 32-MFMA cluster:
//   issue rawA(sk+2) + glds B(sk+1)->sB[nxt] ; SGB(0);
//   ds_read frags [cb]; MFMA x32; SGB(0);
//   cvt rawA(sk+1) (vmcnt long satisfied) -> ds_write sA[nxt]; bar.
// Floors: A-HBM 21.3us, MFMA 16.6us, B-L2 7.8us.
// ---------------------------------------------------------------------------
__global__ __launch_bounds__(256, 2) void k_energy(
        const float* __restrict__ enc,          // [65536][512]
        const float* __restrict__ cov,          // [65536]
        const float* __restrict__ base,         // [64][512]
        const unsigned short* __restrict__ wfrag,
        const float* __restrict__ Wcov,         // [512]
        const float* __restrict__ Wfull,        // [512]
        float* __restrict__ energy)             // [65536]
{
    __shared__ __align__(16) unsigned char sB[2][32768]; // [cw(8)][n(4)][lane][16B]
    __shared__ __align__(16) unsigned char sA[2][4096];  // [m(4)][lane][16B]
    __shared__ float sCov[64];
    __shared__ float sEp[4][64];

    const int tid  = threadIdx.x;
    const int wid  = tid >> 6, lane = tid & 63;
    const int r0   = blockIdx.x * 64;
    const int b    = r0 >> 10;

    if (tid < 64) sCov[tid] = cov[r0 + tid];

    f32x4 acc[4][8];
    #pragma unroll
    for (int m = 0; m < 4; ++m)
        #pragma unroll
        for (int nn = 0; nn < 8; ++nn) acc[m][nn] = (f32x4){0.f, 0.f, 0.f, 0.f};

    // A staging: thread t covers row R=t>>2, 8 floats at q*8 within a 32-k step
    const int R = tid >> 2, q = tid & 3;
    const float* arow = enc + (size_t)(r0 + R) * NE + q * 8;
    const int awByte = (R >> 4) * 1024 + (q * 16 + (R & 15)) * 16;
    // B glds: wave w stages 8 chunks j: cw=2w+(j>>2), n=j&3
    // global byte = stepByte + (2w+(j>>2))*8192 + (j&3)*1024 + lane*16
    //   stepByte(sk) = (sk>>1)*65536 + (sk&1)*4096
    // dest byte (in sB buf) = w*8192 + (j>>2)*4096 + (j&3)*1024 + lane*16
    const unsigned char* bsrc0 = (const unsigned char*)wfrag
                               + (size_t)(2 * wid) * 8192 + lane * 16;

    float4 rawA[2], rawB[2];   // two prefetch sets, 8 floats each

    // ---- prologue: A(0)->sA[0] direct; glds B(0)->sB[0]; raw A(1)->set1
    {
        float4 p0 = *(const float4*)(arow);
        float4 p1 = *(const float4*)(arow + 4);
        *(uint4*)(sA[0] + awByte) = pack8(p0, p1);
        #pragma unroll
        for (int j = 0; j < 8; ++j){
            __builtin_amdgcn_global_load_lds(
                (__attribute__((address_space(1))) void*)(bsrc0 + (j >> 2) * 8192 + (j & 3) * 1024),
                (__attribute__((address_space(3))) void*)(sB[0] + wid * 8192 + (j >> 2) * 4096 + (j & 3) * 1024 + lane * 16),
                16, 0, 0);
        }
        rawB[0] = *(const float4*)(arow + 32);
        rawB[1] = *(const float4*)(arow + 36);
    }
    __syncthreads();

    #pragma unroll
    for (int sk = 0; sk < 16; ++sk){
        const int cb = sk & 1;
        // ---- phase 1: issue rawA(sk+2) and glds B(sk+1) (no waits)
        if (sk <= 13){
            const float* ap = arow + (sk + 2) * 32;
            if ((sk & 1) == 0){ rawA[0] = *(const float4*)(ap); rawA[1] = *(const float4*)(ap + 4); }
            else              { rawB[0] = *(const float4*)(ap); rawB[1] = *(const float4*)(ap + 4); }
        }
        if (sk <= 14){
            const size_t stepByte = (size_t)((sk + 1) >> 1) * 65536 + ((sk + 1) & 1) * 4096;
            const unsigned char* bs = bsrc0 + stepByte;
            unsigned char* bd = sB[cb ^ 1] + wid * 8192 + lane * 16;
            #pragma unroll
            for (int j = 0; j < 8; ++j){
                __builtin_amdgcn_global_load_lds(
                    (__attribute__((address_space(1))) void*)(bs + (j >> 2) * 8192 + (j & 3) * 1024),
                    (__attribute__((address_space(3))) void*)(bd + (j >> 2) * 4096 + (j & 3) * 1024),
                    16, 0, 0);
            }
        }
        __builtin_amdgcn_sched_barrier(0);
        // ---- phase 2: ds_read fragments + 32 MFMAs (regs only)
        bf16x8 af[4];
        #pragma unroll
        for (int m = 0; m < 4; ++m)
            af[m] = *(const bf16x8*)(sA[cb] + m * 1024 + lane * 16);
        bf16x8 bf[8];
        #pragma unroll
        for (int nn = 0; nn < 8; ++nn)
            bf[nn] = *(const bf16x8*)(sB[cb] + wid * 8192 + (nn >> 2) * 4096 + (nn & 3) * 1024 + lane * 16);
        #pragma unroll
        for (int nn = 0; nn < 8; ++nn)
            #pragma unroll
            for (int m = 0; m < 4; ++m)
                acc[m][nn] = __builtin_amdgcn_mfma_f32_16x16x32_bf16(
                                af[m], bf[nn], acc[m][nn], 0, 0, 0);
        __builtin_amdgcn_sched_barrier(0);
        // ---- phase 3: cvt rawA(sk+1) (loaded last step) -> sA[nxt]
        if (sk <= 14){
            if ((sk & 1) == 0) *(uint4*)(sA[cb ^ 1] + awByte) = pack8(rawB[0], rawB[1]);
            else               *(uint4*)(sA[cb ^ 1] + awByte) = pack8(rawA[0], rawA[1]);
        }
        __syncthreads();
    }

    // ---- epilogue: relu(acc + base + cov*Wcov) * Wfull, reduce over cols
    const int c0 = wid * 128 + (lane & 15);
    float basev[8], wcovv[8], wfullv[8];
    #pragma unroll
    for (int nn = 0; nn < 8; ++nn){
        const int c = c0 + ((nn >> 2) * 64) + (nn & 3) * 16;
        basev[nn]  = base[b * 512 + c];
        wcovv[nn]  = Wcov[c];
        wfullv[nn] = Wfull[c];
    }
    const int hi = lane >> 4;                 // D row = m*16 + 4*hi + reg
    float covr[4][4];
    #pragma unroll
    for (int m = 0; m < 4; ++m)
        #pragma unroll
        for (int r = 0; r < 4; ++r) covr[m][r] = sCov[m*16 + 4*hi + r];
    float epv[4][4] = {};
    #pragma unroll
    for (int m = 0; m < 4; ++m)
        #pragma unroll
        for (int nn = 0; nn < 8; ++nn)
            #pragma unroll
            for (int r = 0; r < 4; ++r){
                float v = acc[m][nn][r] + basev[nn] + covr[m][r] * wcovv[nn];
                v = fmaxf(v, 0.f);
                epv[m][r] += v * wfullv[nn];
            }
    #pragma unroll
    for (int m = 0; m < 4; ++m)
        #pragma unroll
        for (int r = 0; r < 4; ++r){
            float v = epv[m][r];
            v += __shfl_xor(v, 1);
            v += __shfl_xor(v, 2);
            v += __shfl_xor(v, 4);
            v += __shfl_xor(v, 8);
            epv[m][r] = v;
        }
    if ((lane & 15) == 0){
        #pragma unroll
        for (int m = 0; m < 4; ++m)
            #pragma unroll
            for (int r = 0; r < 4; ++r)
                sEp[wid][m*16 + 4*hi + r] = epv[m][r];
    }
    __syncthreads();
    if (tid < 64)
        energy[r0 + tid] = sEp[0][tid] + sEp[1][tid] + sEp[2][tid] + sEp[3][tid];
}

// ---------------------------------------------------------------------------
// Kernel 2: softmax over L, alpha/new_coverage writes, weighted encoding.
// ---------------------------------------------------------------------------
#define AWE_OFF   0
#define ALPHA_OFF 32768
#define NCOV_OFF  98304

__global__ __launch_bounds__(256) void k_finish(
        const float* __restrict__ enc, const float* __restrict__ cov,
        const float* __restrict__ energy, float* __restrict__ out)
{
    const int bid = blockIdx.x;
    const int b = bid >> 3, ec = bid & 7;
    const int tid = threadIdx.x;
    __shared__ float sa[1024];
    __shared__ float rb[16];
    __shared__ float ps2[16][64];

    float4 ev = ((const float4*)(energy + b * 1024))[tid];
    float mx = fmaxf(fmaxf(ev.x, ev.y), fmaxf(ev.z, ev.w));
    #pragma unroll
    for (int off = 32; off; off >>= 1) mx = fmaxf(mx, __shfl_xor(mx, off));
    if ((tid & 63) == 0) rb[tid >> 6] = mx;
    __syncthreads();
    mx = fmaxf(fmaxf(rb[0], rb[1]), fmaxf(rb[2], rb[3]));
    float e0 = __expf(ev.x - mx), e1 = __expf(ev.y - mx),
          e2 = __expf(ev.z - mx), e3 = __expf(ev.w - mx);
    ((float4*)sa)[tid] = make_float4(e0, e1, e2, e3);
    float sm = e0 + e1 + e2 + e3;
    #pragma unroll
    for (int off = 32; off; off >>= 1) sm += __shfl_xor(sm, off);
    if ((tid & 63) == 0) rb[8 + (tid >> 6)] = sm;
    __syncthreads();
    const float inv = 1.0f / (rb[8] + rb[9] + rb[10] + rb[11]);

    if (ec == 0){
        #pragma unroll
        for (int i = 0; i < 4; ++i){
            const int idx = tid + i * 256;
            const float a = sa[idx] * inv;
            out[ALPHA_OFF + b * 1024 + idx] = a;
            out[NCOV_OFF  + b * 1024 + idx] = cov[b * 1024 + idx] + a;
        }
    }

    // weighted sum: thread = (row-group rg of 64 rows, col-group cg of 4 cols)
    const int cg = tid & 15, rg = tid >> 4;
    const float4* ep = (const float4*)(enc + (size_t)(b * 1024 + rg * 64) * 512)
                     + ec * 16 + cg;
    const float* w = sa + rg * 64;
    float ax = 0.f, ay = 0.f, az = 0.f, aw = 0.f;
    #pragma unroll 8
    for (int l = 0; l < 64; ++l){
        float4 e4 = ep[(size_t)l * 128];
        const float wl = w[l];
        ax += e4.x * wl; ay += e4.y * wl; az += e4.z * wl; aw += e4.w * wl;
    }
    ps2[rg][cg * 4 + 0] = ax;
    ps2[rg][cg * 4 + 1] = ay;
    ps2[rg][cg * 4 + 2] = az;
    ps2[rg][cg * 4 + 3] = aw;
    __syncthreads();
    if (tid < 64){
        float s = 0.f;
        #pragma unroll
        for (int g = 0; g < 16; ++g) s += ps2[g][tid];
        out[AWE_OFF + b * 512 + ec * 64 + tid] = s * inv;
    }
}

// ---------------------------------------------------------------------------
extern "C" void kernel_launch(void* const* d_in, const int* in_sizes, int n_in,
                              void* d_out, int out_size, void* d_ws, size_t ws_size,
                              hipStream_t stream){
    const float* enc   = (const float*)d_in[0];
    const float* dh    = (const float*)d_in[1];
    const float* cov   = (const float*)d_in[2];
    const float* Wenc  = (const float*)d_in[3];
    const float* benc  = (const float*)d_in[4];
    const float* Wdec  = (const float*)d_in[5];
    const float* bdec  = (const float*)d_in[6];
    const float* Wcov  = (const float*)d_in[7];
    const float* bcov  = (const float*)d_in[8];
    const float* Wfull = (const float*)d_in[9];
    // d_in[10] (b_full) unused: softmax is shift-invariant.
    float* out = (float*)d_out;

    unsigned short* wfrag = (unsigned short*)d_ws;              // 512 KB
    float* base   = (float*)((char*)d_ws + 512 * 1024);        // 128 KB
    float* energy = (float*)((char*)d_ws + 640 * 1024);        // 256 KB

    k_prep  <<<640,  256, 0, stream>>>(Wenc, wfrag, dh, Wdec, bdec, benc, bcov, base);
    k_energy<<<1024, 256, 0, stream>>>(enc, cov, base, wfrag, Wcov, Wfull, energy);
    k_finish<<<512,  256, 0, stream>>>(enc, cov, energy, out);
}